// Round 2
// baseline (637.324 us; speedup 1.0000x reference)
//
#include <hip/hip_runtime.h>
#include <hip/hip_bf16.h>

typedef __attribute__((ext_vector_type(4))) float f32x4;
typedef __attribute__((ext_vector_type(8))) short short8;

__device__ __forceinline__ float bf2f(unsigned short u){
  union { unsigned u32; float f; } v; v.u32 = ((unsigned)u) << 16; return v.f;
}
__device__ __forceinline__ unsigned short f2bf(float f){
  union { float f; unsigned u; } v; v.f = f;
  unsigned x = v.u;
  unsigned r = x + 0x7fffu + ((x >> 16) & 1u);
  return (unsigned short)(r >> 16);
}

// ---------------------------------------------------------------------------
// K0: repack weights/bias/act/gamma/beta (all fp32 inputs) into ws.
// Row order j in [0,96): 0..15 q (h*4+o), 16..31 k, 32..95 v (h*16+o).
// Wall[c][j] (c-major, 96 wide), ball[j], aall[j], Gall[j][f], Ball[j][f],
// Wps[c][o] = Wp[o][c].
// ---------------------------------------------------------------------------
__global__ __launch_bounds__(256) void prep_kernel(
    const float* Wq, const float* bq, const float* aq,
    const float* gq, const float* beq,
    const float* Wk, const float* bk, const float* ak,
    const float* gk, const float* bek,
    const float* Wv, const float* bv, const float* av,
    const float* gv, const float* bev,
    const float* Wp,
    float* Wall, float* ball, float* aall, float* Gall, float* Ball, float* Wps)
{
  int idx = blockIdx.x * 256 + threadIdx.x;
  if (idx < 6144) {                       // Wall
    int c = idx / 96, j = idx % 96;
    float w;
    if (j < 16)      w = Wq[j * 64 + c];
    else if (j < 32) w = Wk[(j - 16) * 64 + c];
    else             w = Wv[(j - 32) * 64 + c];
    Wall[c * 96 + j] = w;
  } else if (idx < 6240) {                // ball / aall
    int j = idx - 6144;
    float b, a;
    if (j < 16)      { b = bq[j];      a = aq[j >> 2]; }
    else if (j < 32) { b = bk[j - 16]; a = ak[(j - 16) >> 2]; }
    else             { b = bv[j - 32]; a = av[(j - 32) >> 4]; }
    ball[j] = b; aall[j] = a;
  } else if (idx < 6240 + 12288) {        // Gall / Ball
    int r = idx - 6240; int j = r >> 7;
    float g, be;
    if (j < 16)      { g = gq[r];        be = beq[r]; }
    else if (j < 32) { g = gk[r - 2048]; be = bek[r - 2048]; }
    else             { g = gv[r - 4096]; be = bev[r - 4096]; }
    Gall[r] = g; Ball[r] = be;
  } else if (idx < 6240 + 12288 + 4096) { // Wps
    int r = idx - 6240 - 12288; int o = r >> 6, c = r & 63;
    Wps[c * 64 + o] = Wp[o * 64 + c];
  }
}

// ---------------------------------------------------------------------------
// K1: fused QKV projection + bias + PReLU + ChannelNorm + gamma/beta.
// One block per (t,b). fblk=tid&31 (4 f each), rblk=tid>>5 (12 j each).
// x fp32 in, qf/kf/vf bf16 out.
// ---------------------------------------------------------------------------
__global__ __launch_bounds__(256) void qkv_kernel(
    const float* __restrict__ x,
    const float* __restrict__ Wall, const float* __restrict__ ball,
    const float* __restrict__ aall, const float* __restrict__ Gall,
    const float* __restrict__ Ball,
    unsigned short* __restrict__ qf, unsigned short* __restrict__ kf,
    unsigned short* __restrict__ vf)
{
  __shared__ float xl[64 * 128];
  __shared__ float wl[64 * 96];
  __shared__ float bias_l[96], a_l[96], rowsum[96], rowsq[96];
  __shared__ float gmean[12], ginv[12];

  int tid = threadIdx.x;
  int t = blockIdx.x, b = blockIdx.y;

  // stage x[b,:,t,:] -> LDS (fp32, float4)
  const float* xp = x + ((long)(b * 64) * 1024 + t) * 128;
  #pragma unroll
  for (int i = 0; i < 8; i++) {
    int id = tid + i * 256;         // 2048 float4 chunks
    int c = id >> 5, f4 = (id & 31) * 4;
    *(f32x4*)&xl[c * 128 + f4] = *(const f32x4*)(xp + (long)c * 131072 + f4);
  }
  #pragma unroll
  for (int i = 0; i < 6; i++) {     // 1536 float4 = 6144 floats
    int id = tid + i * 256;
    ((f32x4*)wl)[id] = ((const f32x4*)Wall)[id];
  }
  if (tid < 96) { bias_l[tid] = ball[tid]; a_l[tid] = aall[tid]; }
  __syncthreads();

  int fblk = tid & 31, rblk = tid >> 5;
  int f0 = fblk * 4, j0 = rblk * 12;

  float acc[12][4];
  #pragma unroll
  for (int jj = 0; jj < 12; jj++)
    #pragma unroll
    for (int ff = 0; ff < 4; ff++) acc[jj][ff] = 0.f;

  for (int c = 0; c < 64; c++) {
    f32x4 xv = *(const f32x4*)&xl[c * 128 + f0];
    const float* wr = &wl[c * 96 + j0];
    f32x4 w0 = *(const f32x4*)(wr);
    f32x4 w1 = *(const f32x4*)(wr + 4);
    f32x4 w2 = *(const f32x4*)(wr + 8);
    #pragma unroll
    for (int jj = 0; jj < 4; jj++) {
      #pragma unroll
      for (int ff = 0; ff < 4; ff++) {
        acc[jj][ff]     += w0[jj] * xv[ff];
        acc[jj + 4][ff] += w1[jj] * xv[ff];
        acc[jj + 8][ff] += w2[jj] * xv[ff];
      }
    }
  }

  // bias + PReLU
  #pragma unroll
  for (int jj = 0; jj < 12; jj++) {
    int j = j0 + jj;
    float bb = bias_l[j], aa = a_l[j];
    #pragma unroll
    for (int ff = 0; ff < 4; ff++) {
      float v = acc[jj][ff] + bb;
      acc[jj][ff] = v > 0.f ? v : aa * v;
    }
  }

  // per-row sums over f: 4 local + butterfly across the 32-lane half-wave
  #pragma unroll
  for (int jj = 0; jj < 12; jj++) {
    float s  = acc[jj][0] + acc[jj][1] + acc[jj][2] + acc[jj][3];
    float sq = acc[jj][0]*acc[jj][0] + acc[jj][1]*acc[jj][1]
             + acc[jj][2]*acc[jj][2] + acc[jj][3]*acc[jj][3];
    #pragma unroll
    for (int m = 1; m <= 16; m <<= 1) {
      s  += __shfl_xor(s,  m, 64);
      sq += __shfl_xor(sq, m, 64);
    }
    if (fblk == 0) { rowsum[j0 + jj] = s; rowsq[j0 + jj] = sq; }
  }
  __syncthreads();

  // group stats: g<8 -> 4 rows (q/k heads), g>=8 -> 16 rows (v heads)
  if (tid < 12) {
    int g = tid, r0, nr;
    if (g < 8) { r0 = g * 4; nr = 4; }
    else       { r0 = 32 + (g - 8) * 16; nr = 16; }
    float s = 0.f, sq = 0.f;
    for (int r = 0; r < nr; r++) { s += rowsum[r0 + r]; sq += rowsq[r0 + r]; }
    float cnt = (float)(nr * 128);
    float mean = s / cnt;
    float var = fmaxf(sq / cnt - mean * mean, 0.f);
    gmean[g] = mean;
    ginv[g] = rsqrtf(var + 1e-5f);
  }
  __syncthreads();

  // normalize + gamma/beta + write bf16 to attention layouts
  #pragma unroll
  for (int jj = 0; jj < 12; jj++) {
    int j = j0 + jj;
    int g = (j < 32) ? (j >> 2) : (8 + ((j - 32) >> 4));
    float mean = gmean[g], inv = ginv[g];
    f32x4 gg = *(const f32x4*)&Gall[j * 128 + f0];
    f32x4 bb = *(const f32x4*)&Ball[j * 128 + f0];
    ushort4 o;
    o.x = f2bf((acc[jj][0] - mean) * inv * gg[0] + bb[0]);
    o.y = f2bf((acc[jj][1] - mean) * inv * gg[1] + bb[1]);
    o.z = f2bf((acc[jj][2] - mean) * inv * gg[2] + bb[2]);
    o.w = f2bf((acc[jj][3] - mean) * inv * gg[3] + bb[3]);
    unsigned short* dst;
    if (j < 16) {
      int h = j >> 2, oo = j & 3;
      dst = qf + (((long)(h * 4 + b) * 1024 + t) * 512 + oo * 128 + f0);
    } else if (j < 32) {
      int jm = j - 16; int h = jm >> 2, oo = jm & 3;
      dst = kf + (((long)(h * 4 + b) * 1024 + t) * 512 + oo * 128 + f0);
    } else {
      int jm = j - 32; int h = jm >> 4, oo = jm & 15;
      dst = vf + (((long)(h * 4 + b) * 1024 + t) * 2048 + oo * 128 + f0);
    }
    *(ushort4*)dst = o;
  }
}

// ---------------------------------------------------------------------------
// K2: transpose vf[n][t][dv] -> vfT[n][dv][t]  (64x64 tiles via LDS, bf16)
// ---------------------------------------------------------------------------
__global__ __launch_bounds__(256) void transpose_v(
    const unsigned short* __restrict__ vf, unsigned short* __restrict__ vfT)
{
  __shared__ unsigned short tile[64][65];
  int n = blockIdx.z;
  int d0 = blockIdx.x * 64, t0 = blockIdx.y * 64;
  int tid = threadIdx.x;
  int cr = tid >> 4, cc = (tid & 15) * 4;

  const unsigned short* src = vf + ((long)n * 1024 + t0) * 2048 + d0;
  #pragma unroll
  for (int i = 0; i < 4; i++) {
    int r = cr + i * 16;   // t-local
    ushort4 u = *(const ushort4*)(src + (long)r * 2048 + cc);
    tile[r][cc + 0] = u.x; tile[r][cc + 1] = u.y;
    tile[r][cc + 2] = u.z; tile[r][cc + 3] = u.w;
  }
  __syncthreads();
  unsigned short* dst = vfT + ((long)n * 2048 + d0) * 1024 + t0;
  #pragma unroll
  for (int i = 0; i < 4; i++) {
    int r = cr + i * 16;   // d-local
    ushort4 u;
    u.x = tile[cc + 0][r]; u.y = tile[cc + 1][r];
    u.z = tile[cc + 2][r]; u.w = tile[cc + 3][r];
    *(ushort4*)(dst + (long)r * 1024 + cc) = u;
  }
}

// ---------------------------------------------------------------------------
// K3: batched GEMM, D[m][n] = scale * sum_k A[m][k]*B[n][k]  (both k-contig)
// 128x128 tile, BK=32, 4 waves each 64x64 via 16 MFMA (16x16x32 bf16).
// mode 0: Cb[z][m][n] bf16 row-major.  mode 1: fp32 scatter to Cf (b,c,t,f).
// ---------------------------------------------------------------------------
__global__ __launch_bounds__(256) void gemm_bt(
    const unsigned short* __restrict__ A, const unsigned short* __restrict__ B,
    unsigned short* __restrict__ Cb, float* __restrict__ Cf,
    int M, int N, int K, long sA, long sB, long sC, float scale, int mode)
{
  __shared__ unsigned short As[128 * 40];
  __shared__ unsigned short Bs[128 * 40];
  int tid = threadIdx.x;
  int z = blockIdx.z;
  int m0 = blockIdx.y * 128, n0 = blockIdx.x * 128;
  const unsigned short* Ab = A + (long)z * sA + (long)m0 * K;
  const unsigned short* Bb = B + (long)z * sB + (long)n0 * K;
  int lane = tid & 63, wave = tid >> 6;
  int wm = (wave >> 1) * 64, wn = (wave & 1) * 64;
  int l15 = lane & 15, quad = lane >> 4;

  f32x4 acc[4][4];
  #pragma unroll
  for (int i = 0; i < 4; i++)
    #pragma unroll
    for (int j = 0; j < 4; j++) acc[i][j] = {0.f, 0.f, 0.f, 0.f};

  for (int k0 = 0; k0 < K; k0 += 32) {
    #pragma unroll
    for (int i = 0; i < 2; i++) {
      int id = tid + i * 256;           // 512 chunks of 8 ushorts
      int row = id >> 2, c8 = (id & 3) * 8;
      *(short8*)&As[row * 40 + c8] = *(const short8*)(Ab + (long)row * K + k0 + c8);
      *(short8*)&Bs[row * 40 + c8] = *(const short8*)(Bb + (long)row * K + k0 + c8);
    }
    __syncthreads();
    short8 af[4], bfr[4];
    #pragma unroll
    for (int i = 0; i < 4; i++)
      af[i] = *(const short8*)&As[(wm + i * 16 + l15) * 40 + quad * 8];
    #pragma unroll
    for (int j = 0; j < 4; j++)
      bfr[j] = *(const short8*)&Bs[(wn + j * 16 + l15) * 40 + quad * 8];
    #pragma unroll
    for (int i = 0; i < 4; i++)
      #pragma unroll
      for (int j = 0; j < 4; j++)
        acc[i][j] = __builtin_amdgcn_mfma_f32_16x16x32_bf16(af[i], bfr[j], acc[i][j], 0, 0, 0);
    __syncthreads();
  }

  if (mode == 0) {
    #pragma unroll
    for (int i = 0; i < 4; i++)
      #pragma unroll
      for (int j = 0; j < 4; j++) {
        int row = m0 + wm + i * 16 + quad * 4;
        int col = n0 + wn + j * 16 + l15;
        unsigned short* cp = Cb + (long)z * sC + (long)row * N + col;
        #pragma unroll
        for (int r = 0; r < 4; r++)
          cp[(long)r * N] = f2bf(acc[i][j][r] * scale);
      }
  } else {
    int bb = z & 3, h = z >> 2;
    #pragma unroll
    for (int i = 0; i < 4; i++)
      #pragma unroll
      for (int j = 0; j < 4; j++) {
        int row = m0 + wm + i * 16 + quad * 4;   // tq
        int col = n0 + wn + j * 16 + l15;        // dv
        int c = col >> 7, f = col & 127;
        float* cp = Cf + (((long)(bb * 64 + h * 16 + c) * 1024 + row) * 128 + f);
        #pragma unroll
        for (int r = 0; r < 4; r++)
          cp[(long)r * 128] = acc[i][j][r];
      }
  }
}

// ---------------------------------------------------------------------------
// K4: in-place row softmax on P[z][row][0..1024) (bf16, already scaled)
// ---------------------------------------------------------------------------
__global__ __launch_bounds__(256) void softmax_kernel(unsigned short* __restrict__ P)
{
  __shared__ float red[4];
  __shared__ float bmax, bsum;
  int row = blockIdx.x, z = blockIdx.y, tid = threadIdx.x;
  unsigned short* p = P + ((long)z * 1024 + row) * 1024;
  ushort4 u = *(ushort4*)(p + tid * 4);
  float v0 = bf2f(u.x), v1 = bf2f(u.y), v2 = bf2f(u.z), v3 = bf2f(u.w);

  float m = fmaxf(fmaxf(v0, v1), fmaxf(v2, v3));
  #pragma unroll
  for (int s = 1; s <= 32; s <<= 1) m = fmaxf(m, __shfl_xor(m, s, 64));
  if ((tid & 63) == 0) red[tid >> 6] = m;
  __syncthreads();
  if (tid == 0) bmax = fmaxf(fmaxf(red[0], red[1]), fmaxf(red[2], red[3]));
  __syncthreads();
  m = bmax;

  float e0 = __expf(v0 - m), e1 = __expf(v1 - m), e2 = __expf(v2 - m), e3 = __expf(v3 - m);
  float s = e0 + e1 + e2 + e3;
  #pragma unroll
  for (int k = 1; k <= 32; k <<= 1) s += __shfl_xor(s, k, 64);
  if ((tid & 63) == 0) red[tid >> 6] = s;
  __syncthreads();
  if (tid == 0) bsum = red[0] + red[1] + red[2] + red[3];
  __syncthreads();
  float inv = 1.0f / bsum;

  u.x = f2bf(e0 * inv); u.y = f2bf(e1 * inv);
  u.z = f2bf(e2 * inv); u.w = f2bf(e3 * inv);
  *(ushort4*)(p + tid * 4) = u;
}

// ---------------------------------------------------------------------------
// K5: proj (64x64) + bias + PReLU + ChannelNorm over (C,F) + gp/betap + x.
// IN-PLACE on d_out: reads its own (b,:,t,:) fp32 slice, barrier, overwrites.
// ---------------------------------------------------------------------------
__global__ __launch_bounds__(256) void proj_kernel(
    float* __restrict__ io, const float* __restrict__ Wps,
    const float* __restrict__ bp, const float* __restrict__ ap,
    const float* __restrict__ gp, const float* __restrict__ bep,
    const float* __restrict__ x)
{
  __shared__ float xl[64 * 128];
  __shared__ float wl[64 * 64];
  __shared__ float redS[4], redQ[4];
  __shared__ float smean, sinv;

  int tid = threadIdx.x;
  int t = blockIdx.x, b = blockIdx.y;

  float* src = io + ((long)(b * 64) * 1024 + t) * 128;
  #pragma unroll
  for (int i = 0; i < 8; i++) {
    int id = tid + i * 256;
    int c = id >> 5, f4 = (id & 31) * 4;
    *(f32x4*)&xl[c * 128 + f4] = *(const f32x4*)(src + (long)c * 131072 + f4);
  }
  #pragma unroll
  for (int i = 0; i < 4; i++) {       // 1024 float4 = 4096 floats
    int id = tid + i * 256;
    ((f32x4*)wl)[id] = ((const f32x4*)Wps)[id];
  }
  __syncthreads();

  int fblk = tid & 31, rblk = tid >> 5;
  int f0 = fblk * 4, r0 = rblk * 8;

  float acc[8][4];
  #pragma unroll
  for (int rr = 0; rr < 8; rr++)
    #pragma unroll
    for (int ff = 0; ff < 4; ff++) acc[rr][ff] = 0.f;

  for (int c = 0; c < 64; c++) {
    f32x4 xv = *(const f32x4*)&xl[c * 128 + f0];
    f32x4 w0 = *(const f32x4*)&wl[c * 64 + r0];
    f32x4 w1 = *(const f32x4*)&wl[c * 64 + r0 + 4];
    #pragma unroll
    for (int rr = 0; rr < 4; rr++) {
      #pragma unroll
      for (int ff = 0; ff < 4; ff++) {
        acc[rr][ff]     += w0[rr] * xv[ff];
        acc[rr + 4][ff] += w1[rr] * xv[ff];
      }
    }
  }

  float aval = ap[0];
  #pragma unroll
  for (int rr = 0; rr < 8; rr++) {
    float bb = bp[r0 + rr];
    #pragma unroll
    for (int ff = 0; ff < 4; ff++) {
      float v = acc[rr][ff] + bb;
      acc[rr][ff] = v > 0.f ? v : aval * v;
    }
  }

  // single-group reduction over all 64x128
  float s = 0.f, sq = 0.f;
  #pragma unroll
  for (int rr = 0; rr < 8; rr++)
    #pragma unroll
    for (int ff = 0; ff < 4; ff++) { s += acc[rr][ff]; sq += acc[rr][ff] * acc[rr][ff]; }
  #pragma unroll
  for (int m = 1; m <= 32; m <<= 1) { s += __shfl_xor(s, m, 64); sq += __shfl_xor(sq, m, 64); }
  if ((tid & 63) == 0) { redS[tid >> 6] = s; redQ[tid >> 6] = sq; }
  __syncthreads();
  if (tid == 0) {
    float S = redS[0] + redS[1] + redS[2] + redS[3];
    float Q = redQ[0] + redQ[1] + redQ[2] + redQ[3];
    float mean = S / 8192.0f;
    float var = fmaxf(Q / 8192.0f - mean * mean, 0.f);
    smean = mean; sinv = rsqrtf(var + 1e-5f);
  }
  __syncthreads();
  float mean = smean, inv = sinv;

  const float* xb = x + ((long)(b * 64) * 1024 + t) * 128;
  #pragma unroll
  for (int rr = 0; rr < 8; rr++) {
    int c = r0 + rr;
    f32x4 g4 = *(const f32x4*)(gp + c * 128 + f0);
    f32x4 b4 = *(const f32x4*)(bep + c * 128 + f0);
    f32x4 x4 = *(const f32x4*)(xb + (long)c * 131072 + f0);
    f32x4 o;
    o[0] = (acc[rr][0] - mean) * inv * g4[0] + b4[0] + x4[0];
    o[1] = (acc[rr][1] - mean) * inv * g4[1] + b4[1] + x4[1];
    o[2] = (acc[rr][2] - mean) * inv * g4[2] + b4[2] + x4[2];
    o[3] = (acc[rr][3] - mean) * inv * g4[3] + b4[3] + x4[3];
    *(f32x4*)(io + ((long)(b * 64 + c) * 1024 + t) * 128 + f0) = o;
  }
}

// ---------------------------------------------------------------------------
extern "C" void kernel_launch(void* const* d_in, const int* in_sizes, int n_in,
                              void* d_out, int out_size, void* d_ws, size_t ws_size,
                              hipStream_t stream)
{
  const float* x   = (const float*)d_in[0];
  const float* Wq  = (const float*)d_in[1];
  const float* bq  = (const float*)d_in[2];
  const float* aq  = (const float*)d_in[3];
  const float* gq  = (const float*)d_in[4];
  const float* beq = (const float*)d_in[5];
  const float* Wk  = (const float*)d_in[6];
  const float* bk  = (const float*)d_in[7];
  const float* ak  = (const float*)d_in[8];
  const float* gk  = (const float*)d_in[9];
  const float* bek = (const float*)d_in[10];
  const float* Wv  = (const float*)d_in[11];
  const float* bv  = (const float*)d_in[12];
  const float* av  = (const float*)d_in[13];
  const float* gv  = (const float*)d_in[14];
  const float* bev = (const float*)d_in[15];
  const float* Wp  = (const float*)d_in[16];
  const float* bp  = (const float*)d_in[17];
  const float* ap  = (const float*)d_in[18];
  const float* gp  = (const float*)d_in[19];
  const float* bep = (const float*)d_in[20];
  float* out = (float*)d_out;

  char* ws = (char*)d_ws;
  size_t off = 0;
  auto alloc = [&](size_t n) { size_t o = off; off += (n + 255) & ~(size_t)255; return o; };

  float* Wall = (float*)(ws + alloc(6144 * 4));
  float* ball = (float*)(ws + alloc(96 * 4));
  float* aall = (float*)(ws + alloc(96 * 4));
  float* Gall = (float*)(ws + alloc(12288 * 4));
  float* Ball = (float*)(ws + alloc(12288 * 4));
  float* Wps  = (float*)(ws + alloc(4096 * 4));
  unsigned short* qf  = (unsigned short*)(ws + alloc((size_t)16 * 1024 * 512 * 2));
  unsigned short* kf  = (unsigned short*)(ws + alloc((size_t)16 * 1024 * 512 * 2));
  unsigned short* vf  = (unsigned short*)(ws + alloc((size_t)16 * 1024 * 2048 * 2));
  unsigned short* vfT = (unsigned short*)(ws + alloc((size_t)16 * 1024 * 2048 * 2));
  unsigned short* P   = vf;   // vf dead after transpose; P (32 MB) fits in vf (64 MB)

  prep_kernel<<<89, 256, 0, stream>>>(Wq, bq, aq, gq, beq, Wk, bk, ak, gk, bek,
                                      Wv, bv, av, gv, bev, Wp,
                                      Wall, ball, aall, Gall, Ball, Wps);

  qkv_kernel<<<dim3(1024, 4), 256, 0, stream>>>(x, Wall, ball, aall, Gall, Ball,
                                                qf, kf, vf);

  transpose_v<<<dim3(32, 16, 16), 256, 0, stream>>>(vf, vfT);

  // S = scale * Q K^T   -> P (bf16, aliases dead vf)
  gemm_bt<<<dim3(8, 8, 16), 256, 0, stream>>>(
      qf, kf, P, (float*)nullptr, 1024, 1024, 512,
      (long)1024 * 512, (long)1024 * 512, (long)1024 * 1024,
      0.04419417382f /* 1/sqrt(512) */, 0);

  softmax_kernel<<<dim3(1024, 16), 256, 0, stream>>>(P);

  // attn_out = P @ V  -> fp32 scatter directly into d_out (b,c,t,f)
  gemm_bt<<<dim3(16, 8, 16), 256, 0, stream>>>(
      P, vfT, (unsigned short*)nullptr, out, 1024, 2048, 1024,
      (long)1024 * 1024, (long)2048 * 1024, 0, 1.0f, 1);

  // proj + norm + residual, in place on d_out
  proj_kernel<<<dim3(1024, 4), 256, 0, stream>>>(out, Wps, bp, ap, gp, bep, x);
}

// Round 3
// 586.752 us; speedup vs baseline: 1.0862x; 1.0862x over previous
//
#include <hip/hip_runtime.h>
#include <hip/hip_bf16.h>

typedef __attribute__((ext_vector_type(4))) float f32x4;
typedef __attribute__((ext_vector_type(8))) short short8;

__device__ __forceinline__ float bf2f(unsigned short u){
  union { unsigned u32; float f; } v; v.u32 = ((unsigned)u) << 16; return v.f;
}
__device__ __forceinline__ unsigned short f2bf(float f){
  union { float f; unsigned u; } v; v.f = f;
  unsigned x = v.u;
  unsigned r = x + 0x7fffu + ((x >> 16) & 1u);
  return (unsigned short)(r >> 16);
}
__device__ __forceinline__ short8 pack8(f32x4 a, f32x4 b){
  short8 r;
  r[0]=(short)f2bf(a[0]); r[1]=(short)f2bf(a[1]);
  r[2]=(short)f2bf(a[2]); r[3]=(short)f2bf(a[3]);
  r[4]=(short)f2bf(b[0]); r[5]=(short)f2bf(b[1]);
  r[6]=(short)f2bf(b[2]); r[7]=(short)f2bf(b[3]);
  return r;
}

// ---------------------------------------------------------------------------
// K0: tiny prep — ball[96], aall[96] (row order: 0..15 q (h*4+o), 16..31 k,
// 32..95 v (h*16+o)), Wps[c][o] = Wp[o][c].
// ---------------------------------------------------------------------------
__global__ __launch_bounds__(256) void prep_kernel(
    const float* bq, const float* aq, const float* bk, const float* ak,
    const float* bv, const float* av, const float* Wp,
    float* ball, float* aall, float* Wps)
{
  int idx = blockIdx.x * 256 + threadIdx.x;
  if (idx < 96) {
    int j = idx;
    float b, a;
    if (j < 16)      { b = bq[j];      a = aq[j >> 2]; }
    else if (j < 32) { b = bk[j - 16]; a = ak[(j - 16) >> 2]; }
    else             { b = bv[j - 32]; a = av[(j - 32) >> 4]; }
    ball[j] = b; aall[j] = a;
  } else if (idx < 96 + 4096) {
    int r = idx - 96; int o = r >> 6, c = r & 63;
    Wps[c * 64 + o] = Wp[o * 64 + c];
  }
}

// ---------------------------------------------------------------------------
// K1: MFMA QKV: Y[96 x (2t*128f)] = W[96x64] * X[64 x n] per (b, t-pair),
// + bias + PReLU + ChannelNorm(group over (o,f)) + gamma/beta -> bf16 out.
// Block: 256 thr (4 waves); wave w owns n in [w*64, w*64+64), tl = w>>1.
// LDS X layout: [n][c], pitch 64, c-blocks of 8 XOR-swizzled by (n>>1)&7.
// ---------------------------------------------------------------------------
__global__ __launch_bounds__(256, 2) void qkv_mfma(
    const float* __restrict__ x,
    const float* __restrict__ Wq, const float* __restrict__ Wk,
    const float* __restrict__ Wv,
    const float* __restrict__ ball, const float* __restrict__ aall,
    const float* __restrict__ gq, const float* __restrict__ gk,
    const float* __restrict__ gv,
    const float* __restrict__ beq, const float* __restrict__ bek,
    const float* __restrict__ bev,
    unsigned short* __restrict__ qf, unsigned short* __restrict__ kf,
    unsigned short* __restrict__ vf)
{
  __shared__ unsigned short upool[96 * 264];   // xl (32KB) then yl (49.5KB)
  __shared__ float partS[4][96], partQ[4][96];
  __shared__ float gm[2][12], gi[2][12];
  __shared__ float bias_l[96], a_l[96];

  int tid = threadIdx.x;
  int t0 = blockIdx.x * 2, b = blockIdx.y;
  int lane = tid & 63, wave = tid >> 6;
  int l15 = lane & 15, quad = lane >> 4;

  if (tid < 96) { bias_l[tid] = ball[tid]; a_l[tid] = aall[tid]; }

  // ---- A fragments: W rows j = 16*mt + l15, k = 32*ks + quad*8 + [0..8) ----
  const float* wsrc[6] = {
    Wq + l15 * 64, Wk + l15 * 64,
    Wv + l15 * 64, Wv + (16 + l15) * 64,
    Wv + (32 + l15) * 64, Wv + (48 + l15) * 64
  };
  short8 afr[6][2];
  #pragma unroll
  for (int mt = 0; mt < 6; mt++)
    #pragma unroll
    for (int ks = 0; ks < 2; ks++) {
      const float* p = wsrc[mt] + ks * 32 + quad * 8;
      afr[mt][ks] = pack8(*(const f32x4*)p, *(const f32x4*)(p + 4));
    }

  // ---- stage X -> LDS (bf16, transposed to [n][c], swizzled) ----
  unsigned short* xl = upool;
  #pragma unroll
  for (int it = 0; it < 4; it++) {
    int item = it * 256 + tid;      // [0,1024): 8 cb x 128 np
    int cb = item >> 7;             // c-block 0..7
    int np = item & 127;            // n-pair
    int n = np * 2;
    int tl = n >> 7, f = n & 127;
    const float* gp = x + ((long)(b * 64 + cb * 8) * 1024 + t0 + tl) * 128 + f;
    short8 lo, hi;
    #pragma unroll
    for (int w = 0; w < 8; w++) {
      float2 v = *(const float2*)(gp + (long)w * 131072);
      lo[w] = (short)f2bf(v.x);
      hi[w] = (short)f2bf(v.y);
    }
    int perm = cb ^ (np & 7);       // key = (n>>1)&7, same for n and n+1
    *(short8*)&xl[n * 64 + perm * 8]       = lo;
    *(short8*)&xl[(n + 1) * 64 + perm * 8] = hi;
  }
  __syncthreads();

  // ---- MFMA: acc[mt][nt] = W-tile x X-tile ----
  f32x4 acc[6][4];
  #pragma unroll
  for (int mt = 0; mt < 6; mt++)
    #pragma unroll
    for (int nt = 0; nt < 4; nt++)
      acc[mt][nt] = {0.f, 0.f, 0.f, 0.f};

  int nb = wave * 64;
  #pragma unroll
  for (int ks = 0; ks < 2; ks++)
    #pragma unroll
    for (int nt = 0; nt < 4; nt++) {
      int n = nb + nt * 16 + l15;
      int perm = (ks * 4 + quad) ^ ((n >> 1) & 7);
      short8 bfrag = *(const short8*)&xl[n * 64 + perm * 8];
      #pragma unroll
      for (int mt = 0; mt < 6; mt++)
        acc[mt][nt] = __builtin_amdgcn_mfma_f32_16x16x32_bf16(
            afr[mt][ks], bfrag, acc[mt][nt], 0, 0, 0);
    }

  // ---- bias + PReLU, then per-row partial sums over this wave's 64 cols ----
  #pragma unroll
  for (int mt = 0; mt < 6; mt++)
    #pragma unroll
    for (int r = 0; r < 4; r++) {
      int j = mt * 16 + quad * 4 + r;
      float bb = bias_l[j], aa = a_l[j];
      #pragma unroll
      for (int nt = 0; nt < 4; nt++) {
        float v = acc[mt][nt][r] + bb;
        acc[mt][nt][r] = v > 0.f ? v : aa * v;
      }
      float s  = acc[mt][0][r] + acc[mt][1][r] + acc[mt][2][r] + acc[mt][3][r];
      float q2 = acc[mt][0][r]*acc[mt][0][r] + acc[mt][1][r]*acc[mt][1][r]
               + acc[mt][2][r]*acc[mt][2][r] + acc[mt][3][r]*acc[mt][3][r];
      #pragma unroll
      for (int m = 1; m <= 8; m <<= 1) {
        s  += __shfl_xor(s,  m, 64);
        q2 += __shfl_xor(q2, m, 64);
      }
      if (l15 == 0) { partS[wave][j] = s; partQ[wave][j] = q2; }
    }
  __syncthreads();   // xl reads done everywhere; partS/Q complete

  // ---- stash y (pre-norm) to LDS as bf16; compute group stats ----
  unsigned short* yl = upool;   // pitch 264
  #pragma unroll
  for (int mt = 0; mt < 6; mt++)
    #pragma unroll
    for (int nt = 0; nt < 4; nt++) {
      int n = nb + nt * 16 + l15;
      #pragma unroll
      for (int r = 0; r < 4; r++) {
        int j = mt * 16 + quad * 4 + r;
        yl[j * 264 + n] = f2bf(acc[mt][nt][r]);
      }
    }
  if (tid < 24) {
    int g = tid % 12, tl2 = tid / 12;
    int r0 = (g < 4) ? g * 4 : (g < 8) ? 16 + (g - 4) * 4 : 32 + (g - 8) * 16;
    int nr = (g < 8) ? 4 : 16;
    float S = 0.f, Q = 0.f;
    for (int w = tl2 * 2; w < tl2 * 2 + 2; w++)
      for (int r = 0; r < nr; r++) { S += partS[w][r0 + r]; Q += partQ[w][r0 + r]; }
    float cnt = (float)(nr * 128);
    float mean = S / cnt;
    float var = fmaxf(Q / cnt - mean * mean, 0.f);
    gm[tl2][g] = mean;
    gi[tl2][g] = rsqrtf(var + 1e-5f);
  }
  __syncthreads();

  // ---- normalize + gamma/beta + coalesced bf16 store ----
  int ch = tid & 31, jrow = tid >> 5;
  #pragma unroll
  for (int itj = 0; itj < 12; itj++) {
    int j = itj * 8 + jrow;
    int n0 = ch * 8;
    int tl3 = n0 >> 7, f = n0 & 127;
    short8 y8 = *(const short8*)&yl[j * 264 + n0];
    int g = (j < 16) ? (j >> 2) : (j < 32) ? 4 + ((j - 16) >> 2) : 8 + ((j - 32) >> 4);
    float mean = gm[tl3][g], inv = gi[tl3][g];
    const float *gsrc, *bsrc;
    int jo;
    unsigned short* dst;
    if (j < 16) {
      jo = j; gsrc = gq; bsrc = beq;
      int h = j >> 2, o = j & 3;
      dst = qf + (((long)(h * 4 + b) * 1024 + t0 + tl3) * 512 + o * 128 + f);
    } else if (j < 32) {
      jo = j - 16; gsrc = gk; bsrc = bek;
      int h = jo >> 2, o = jo & 3;
      dst = kf + (((long)(h * 4 + b) * 1024 + t0 + tl3) * 512 + o * 128 + f);
    } else {
      jo = j - 32; gsrc = gv; bsrc = bev;
      int h = jo >> 4, o = jo & 15;
      dst = vf + (((long)(h * 4 + b) * 1024 + t0 + tl3) * 2048 + o * 128 + f);
    }
    f32x4 g0 = *(const f32x4*)(gsrc + jo * 128 + f);
    f32x4 g1 = *(const f32x4*)(gsrc + jo * 128 + f + 4);
    f32x4 b0 = *(const f32x4*)(bsrc + jo * 128 + f);
    f32x4 b1 = *(const f32x4*)(bsrc + jo * 128 + f + 4);
    short8 o8;
    #pragma unroll
    for (int i = 0; i < 4; i++) {
      o8[i]     = (short)f2bf((bf2f((unsigned short)y8[i])     - mean) * inv * g0[i] + b0[i]);
      o8[i + 4] = (short)f2bf((bf2f((unsigned short)y8[i + 4]) - mean) * inv * g1[i] + b1[i]);
    }
    *(short8*)dst = o8;
  }
}

// ---------------------------------------------------------------------------
// K2: transpose vf[n][t][dv] -> vfT[n][dv][t]  (64x64 tiles via LDS, bf16)
// ---------------------------------------------------------------------------
__global__ __launch_bounds__(256) void transpose_v(
    const unsigned short* __restrict__ vf, unsigned short* __restrict__ vfT)
{
  __shared__ unsigned short tile[64][65];
  int n = blockIdx.z;
  int d0 = blockIdx.x * 64, t0 = blockIdx.y * 64;
  int tid = threadIdx.x;
  int cr = tid >> 4, cc = (tid & 15) * 4;

  const unsigned short* src = vf + ((long)n * 1024 + t0) * 2048 + d0;
  #pragma unroll
  for (int i = 0; i < 4; i++) {
    int r = cr + i * 16;   // t-local
    ushort4 u = *(const ushort4*)(src + (long)r * 2048 + cc);
    tile[r][cc + 0] = u.x; tile[r][cc + 1] = u.y;
    tile[r][cc + 2] = u.z; tile[r][cc + 3] = u.w;
  }
  __syncthreads();
  unsigned short* dst = vfT + ((long)n * 2048 + d0) * 1024 + t0;
  #pragma unroll
  for (int i = 0; i < 4; i++) {
    int r = cr + i * 16;   // d-local
    ushort4 u;
    u.x = tile[cc + 0][r]; u.y = tile[cc + 1][r];
    u.z = tile[cc + 2][r]; u.w = tile[cc + 3][r];
    *(ushort4*)(dst + (long)r * 1024 + cc) = u;
  }
}

// ---------------------------------------------------------------------------
// K3: batched GEMM, D[m][n] = scale * sum_k A[m][k]*B[n][k]  (both k-contig)
// 128x128 tile, BK=32, 4 waves each 64x64 via 16 MFMA (16x16x32 bf16).
// mode 0: Cb[z][m][n] bf16 row-major.  mode 1: fp32 scatter to Cf (b,c,t,f).
// ---------------------------------------------------------------------------
__global__ __launch_bounds__(256) void gemm_bt(
    const unsigned short* __restrict__ A, const unsigned short* __restrict__ B,
    unsigned short* __restrict__ Cb, float* __restrict__ Cf,
    int M, int N, int K, long sA, long sB, long sC, float scale, int mode)
{
  __shared__ unsigned short As[128 * 40];
  __shared__ unsigned short Bs[128 * 40];
  int tid = threadIdx.x;
  int z = blockIdx.z;
  int m0 = blockIdx.y * 128, n0 = blockIdx.x * 128;
  const unsigned short* Ab = A + (long)z * sA + (long)m0 * K;
  const unsigned short* Bb = B + (long)z * sB + (long)n0 * K;
  int lane = tid & 63, wave = tid >> 6;
  int wm = (wave >> 1) * 64, wn = (wave & 1) * 64;
  int l15 = lane & 15, quad = lane >> 4;

  f32x4 acc[4][4];
  #pragma unroll
  for (int i = 0; i < 4; i++)
    #pragma unroll
    for (int j = 0; j < 4; j++) acc[i][j] = {0.f, 0.f, 0.f, 0.f};

  for (int k0 = 0; k0 < K; k0 += 32) {
    #pragma unroll
    for (int i = 0; i < 2; i++) {
      int id = tid + i * 256;           // 512 chunks of 8 ushorts
      int row = id >> 2, c8 = (id & 3) * 8;
      *(short8*)&As[row * 40 + c8] = *(const short8*)(Ab + (long)row * K + k0 + c8);
      *(short8*)&Bs[row * 40 + c8] = *(const short8*)(Bb + (long)row * K + k0 + c8);
    }
    __syncthreads();
    short8 af[4], bfr[4];
    #pragma unroll
    for (int i = 0; i < 4; i++)
      af[i] = *(const short8*)&As[(wm + i * 16 + l15) * 40 + quad * 8];
    #pragma unroll
    for (int j = 0; j < 4; j++)
      bfr[j] = *(const short8*)&Bs[(wn + j * 16 + l15) * 40 + quad * 8];
    #pragma unroll
    for (int i = 0; i < 4; i++)
      #pragma unroll
      for (int j = 0; j < 4; j++)
        acc[i][j] = __builtin_amdgcn_mfma_f32_16x16x32_bf16(af[i], bfr[j], acc[i][j], 0, 0, 0);
    __syncthreads();
  }

  if (mode == 0) {
    #pragma unroll
    for (int i = 0; i < 4; i++)
      #pragma unroll
      for (int j = 0; j < 4; j++) {
        int row = m0 + wm + i * 16 + quad * 4;
        int col = n0 + wn + j * 16 + l15;
        unsigned short* cp = Cb + (long)z * sC + (long)row * N + col;
        #pragma unroll
        for (int r = 0; r < 4; r++)
          cp[(long)r * N] = f2bf(acc[i][j][r] * scale);
      }
  } else {
    int bb = z & 3, h = z >> 2;
    #pragma unroll
    for (int i = 0; i < 4; i++)
      #pragma unroll
      for (int j = 0; j < 4; j++) {
        int row = m0 + wm + i * 16 + quad * 4;   // tq
        int col = n0 + wn + j * 16 + l15;        // dv
        int c = col >> 7, f = col & 127;
        float* cp = Cf + (((long)(bb * 64 + h * 16 + c) * 1024 + row) * 128 + f);
        #pragma unroll
        for (int r = 0; r < 4; r++)
          cp[(long)r * 128] = acc[i][j][r];
      }
  }
}

// ---------------------------------------------------------------------------
// K4: in-place row softmax on P[z][row][0..1024) (bf16, already scaled)
// ---------------------------------------------------------------------------
__global__ __launch_bounds__(256) void softmax_kernel(unsigned short* __restrict__ P)
{
  __shared__ float red[4];
  __shared__ float bmax, bsum;
  int row = blockIdx.x, z = blockIdx.y, tid = threadIdx.x;
  unsigned short* p = P + ((long)z * 1024 + row) * 1024;
  ushort4 u = *(ushort4*)(p + tid * 4);
  float v0 = bf2f(u.x), v1 = bf2f(u.y), v2 = bf2f(u.z), v3 = bf2f(u.w);

  float m = fmaxf(fmaxf(v0, v1), fmaxf(v2, v3));
  #pragma unroll
  for (int s = 1; s <= 32; s <<= 1) m = fmaxf(m, __shfl_xor(m, s, 64));
  if ((tid & 63) == 0) red[tid >> 6] = m;
  __syncthreads();
  if (tid == 0) bmax = fmaxf(fmaxf(red[0], red[1]), fmaxf(red[2], red[3]));
  __syncthreads();
  m = bmax;

  float e0 = __expf(v0 - m), e1 = __expf(v1 - m), e2 = __expf(v2 - m), e3 = __expf(v3 - m);
  float s = e0 + e1 + e2 + e3;
  #pragma unroll
  for (int k = 1; k <= 32; k <<= 1) s += __shfl_xor(s, k, 64);
  if ((tid & 63) == 0) red[tid >> 6] = s;
  __syncthreads();
  if (tid == 0) bsum = red[0] + red[1] + red[2] + red[3];
  __syncthreads();
  float inv = 1.0f / bsum;

  u.x = f2bf(e0 * inv); u.y = f2bf(e1 * inv);
  u.z = f2bf(e2 * inv); u.w = f2bf(e3 * inv);
  *(ushort4*)(p + tid * 4) = u;
}

// ---------------------------------------------------------------------------
// K5: proj (64x64) + bias + PReLU + ChannelNorm over (C,F) + gp/betap + x.
// IN-PLACE on d_out: reads its own (b,:,t,:) fp32 slice, barrier, overwrites.
// ---------------------------------------------------------------------------
__global__ __launch_bounds__(256) void proj_kernel(
    float* __restrict__ io, const float* __restrict__ Wps,
    const float* __restrict__ bp, const float* __restrict__ ap,
    const float* __restrict__ gp, const float* __restrict__ bep,
    const float* __restrict__ x)
{
  __shared__ float xl[64 * 128];
  __shared__ float wl[64 * 64];
  __shared__ float redS[4], redQ[4];
  __shared__ float smean, sinv;

  int tid = threadIdx.x;
  int t = blockIdx.x, b = blockIdx.y;

  float* src = io + ((long)(b * 64) * 1024 + t) * 128;
  #pragma unroll
  for (int i = 0; i < 8; i++) {
    int id = tid + i * 256;
    int c = id >> 5, f4 = (id & 31) * 4;
    *(f32x4*)&xl[c * 128 + f4] = *(const f32x4*)(src + (long)c * 131072 + f4);
  }
  #pragma unroll
  for (int i = 0; i < 4; i++) {
    int id = tid + i * 256;
    ((f32x4*)wl)[id] = ((const f32x4*)Wps)[id];
  }
  __syncthreads();

  int fblk = tid & 31, rblk = tid >> 5;
  int f0 = fblk * 4, r0 = rblk * 8;

  float acc[8][4];
  #pragma unroll
  for (int rr = 0; rr < 8; rr++)
    #pragma unroll
    for (int ff = 0; ff < 4; ff++) acc[rr][ff] = 0.f;

  for (int c = 0; c < 64; c++) {
    f32x4 xv = *(const f32x4*)&xl[c * 128 + f0];
    f32x4 w0 = *(const f32x4*)&wl[c * 64 + r0];
    f32x4 w1 = *(const f32x4*)&wl[c * 64 + r0 + 4];
    #pragma unroll
    for (int rr = 0; rr < 4; rr++) {
      #pragma unroll
      for (int ff = 0; ff < 4; ff++) {
        acc[rr][ff]     += w0[rr] * xv[ff];
        acc[rr + 4][ff] += w1[rr] * xv[ff];
      }
    }
  }

  float aval = ap[0];
  #pragma unroll
  for (int rr = 0; rr < 8; rr++) {
    float bb = bp[r0 + rr];
    #pragma unroll
    for (int ff = 0; ff < 4; ff++) {
      float v = acc[rr][ff] + bb;
      acc[rr][ff] = v > 0.f ? v : aval * v;
    }
  }

  float s = 0.f, sq = 0.f;
  #pragma unroll
  for (int rr = 0; rr < 8; rr++)
    #pragma unroll
    for (int ff = 0; ff < 4; ff++) { s += acc[rr][ff]; sq += acc[rr][ff] * acc[rr][ff]; }
  #pragma unroll
  for (int m = 1; m <= 32; m <<= 1) { s += __shfl_xor(s, m, 64); sq += __shfl_xor(sq, m, 64); }
  if ((tid & 63) == 0) { redS[tid >> 6] = s; redQ[tid >> 6] = sq; }
  __syncthreads();
  if (tid == 0) {
    float S = redS[0] + redS[1] + redS[2] + redS[3];
    float Q = redQ[0] + redQ[1] + redQ[2] + redQ[3];
    float mean = S / 8192.0f;
    float var = fmaxf(Q / 8192.0f - mean * mean, 0.f);
    smean = mean; sinv = rsqrtf(var + 1e-5f);
  }
  __syncthreads();
  float mean = smean, inv = sinv;

  const float* xb = x + ((long)(b * 64) * 1024 + t) * 128;
  #pragma unroll
  for (int rr = 0; rr < 8; rr++) {
    int c = r0 + rr;
    f32x4 g4 = *(const f32x4*)(gp + c * 128 + f0);
    f32x4 b4 = *(const f32x4*)(bep + c * 128 + f0);
    f32x4 x4 = *(const f32x4*)(xb + (long)c * 131072 + f0);
    f32x4 o;
    o[0] = (acc[rr][0] - mean) * inv * g4[0] + b4[0] + x4[0];
    o[1] = (acc[rr][1] - mean) * inv * g4[1] + b4[1] + x4[1];
    o[2] = (acc[rr][2] - mean) * inv * g4[2] + b4[2] + x4[2];
    o[3] = (acc[rr][3] - mean) * inv * g4[3] + b4[3] + x4[3];
    *(f32x4*)(io + ((long)(b * 64 + c) * 1024 + t) * 128 + f0) = o;
  }
}

// ---------------------------------------------------------------------------
extern "C" void kernel_launch(void* const* d_in, const int* in_sizes, int n_in,
                              void* d_out, int out_size, void* d_ws, size_t ws_size,
                              hipStream_t stream)
{
  const float* x   = (const float*)d_in[0];
  const float* Wq  = (const float*)d_in[1];
  const float* bq  = (const float*)d_in[2];
  const float* aq  = (const float*)d_in[3];
  const float* gq  = (const float*)d_in[4];
  const float* beq = (const float*)d_in[5];
  const float* Wk  = (const float*)d_in[6];
  const float* bk  = (const float*)d_in[7];
  const float* ak  = (const float*)d_in[8];
  const float* gk  = (const float*)d_in[9];
  const float* bek = (const float*)d_in[10];
  const float* Wv  = (const float*)d_in[11];
  const float* bv  = (const float*)d_in[12];
  const float* av  = (const float*)d_in[13];
  const float* gv  = (const float*)d_in[14];
  const float* bev = (const float*)d_in[15];
  const float* Wp  = (const float*)d_in[16];
  const float* bp  = (const float*)d_in[17];
  const float* ap  = (const float*)d_in[18];
  const float* gp  = (const float*)d_in[19];
  const float* bep = (const float*)d_in[20];
  float* out = (float*)d_out;

  char* ws = (char*)d_ws;
  size_t off = 0;
  auto alloc = [&](size_t n) { size_t o = off; off += (n + 255) & ~(size_t)255; return o; };

  float* ball = (float*)(ws + alloc(96 * 4));
  float* aall = (float*)(ws + alloc(96 * 4));
  float* Wps  = (float*)(ws + alloc(4096 * 4));
  unsigned short* qf  = (unsigned short*)(ws + alloc((size_t)16 * 1024 * 512 * 2));
  unsigned short* kf  = (unsigned short*)(ws + alloc((size_t)16 * 1024 * 512 * 2));
  unsigned short* vf  = (unsigned short*)(ws + alloc((size_t)16 * 1024 * 2048 * 2));
  unsigned short* vfT = (unsigned short*)(ws + alloc((size_t)16 * 1024 * 2048 * 2));
  unsigned short* P   = vf;   // vf dead after transpose; P (32 MB) fits in vf (64 MB)

  prep_kernel<<<17, 256, 0, stream>>>(bq, aq, bk, ak, bv, av, Wp,
                                      ball, aall, Wps);

  qkv_mfma<<<dim3(512, 4), 256, 0, stream>>>(
      x, Wq, Wk, Wv, ball, aall, gq, gk, gv, beq, bek, bev, qf, kf, vf);

  transpose_v<<<dim3(32, 16, 16), 256, 0, stream>>>(vf, vfT);

  // S = scale * Q K^T   -> P (bf16, aliases dead vf)
  gemm_bt<<<dim3(8, 8, 16), 256, 0, stream>>>(
      qf, kf, P, (float*)nullptr, 1024, 1024, 512,
      (long)1024 * 512, (long)1024 * 512, (long)1024 * 1024,
      0.04419417382f /* 1/sqrt(512) */, 0);

  softmax_kernel<<<dim3(1024, 16), 256, 0, stream>>>(P);

  // attn_out = P @ V  -> fp32 scatter directly into d_out (b,c,t,f)
  gemm_bt<<<dim3(16, 8, 16), 256, 0, stream>>>(
      P, vfT, (unsigned short*)nullptr, out, 1024, 2048, 1024,
      (long)1024 * 1024, (long)2048 * 1024, 0, 1.0f, 1);

  // proj + norm + residual, in place on d_out
  proj_kernel<<<dim3(1024, 4), 256, 0, stream>>>(out, Wps, bp, ap, gp, bep, x);
}